// Round 2
// baseline (183.955 us; speedup 1.0000x reference)
//
#include <hip/hip_runtime.h>

#define HH 64
#define WW 64
#define NN 4096
#define DZc 128
#define KSPLIT 6
#define BK 64

typedef short v8s __attribute__((ext_vector_type(8)));
typedef float v4f __attribute__((ext_vector_type(4)));

__device__ __forceinline__ unsigned rnd_bf(float f){
  union { float f; unsigned u; } c; c.f = f;
  return c.u + 0x8000u;
}

__device__ __forceinline__ unsigned pack2(float lo, float hi){
  return __builtin_amdgcn_perm(rnd_bf(hi), rnd_bf(lo), 0x07060302u);
}

__device__ __forceinline__ float fexp2(float x){
  return __builtin_amdgcn_exp2f(x);
}

__global__ void init_out_kernel(const float4* __restrict__ zc_on,
                                const int* __restrict__ ignore,
                                float4* __restrict__ out){
  int i = blockIdx.x * blockDim.x + threadIdx.x;
  float4 v = zc_on[i];
  if (ignore[0]) { v.x = 0.f; v.y = 0.f; v.z = 0.f; v.w = 0.f; }
  out[i] = v;
}

// 768 blocks (4 b x 32 mt x 6 ks) = exactly 3 blocks/CU resident (LDS 49.9KB).
// Per k-tile: [barrier] A-build (shared bf16 A-tile from gtab) + Z-stage
// [barrier] MFMA consume + gtab stage for next tile (double-buffered).
__global__ void setconv_gemm_kernel(const float* __restrict__ xc_off,
                                    const float* __restrict__ xc_on,
                                    const float* __restrict__ zc_off,
                                    const float* __restrict__ lsp,
                                    float* __restrict__ out)
{
  __shared__ unsigned short At[128][72];   // A bf16 [m][k], row 144B
  __shared__ unsigned short zt[128][72];   // Z^T bf16 [d][k]
  __shared__ float gtab[2][24][68];        // dbuf: rows 0-15 gy, 16-23 gx

  const int tid = threadIdx.x;
  const int bid = blockIdx.x;
  const int ks  = bid % KSPLIT;
  const int rem = bid / KSPLIT;
  const int mt  = rem & 31;
  const int b   = rem >> 5;
  const int iy0 = (mt >> 3) * 16;
  const int ix0 = (mt & 7) * 8;
  const int kt0 = ks * 10 + (ks < 4 ? ks : 4);   // 0,11,22,33,44,54
  const int nkt = (ks < 4) ? 11 : 10;

  const float lsy = 1e-5f + log1pf(expf(lsp[0]));
  const float lsx = 1e-5f + log1pf(expf(lsp[1]));
  const float LOG2E = 1.44269504088896340736f;
  const float ay = -0.5f * LOG2E / (lsy * lsy);
  const float ax = -0.5f * LOG2E / (lsx * lsx);

  // ---- gtab staging constants: 6 rows per thread at col gk
  const int gk = tid & 63;
  const int grow0 = tid >> 6;
  float gc[6], ga[6];
  #pragma unroll
  for (int i = 0; i < 6; ++i){
    int row = grow0 + 4 * i;
    if (i < 4){ gc[i] = xc_on[((b * HH + iy0 + row) * WW) * 2];       ga[i] = ay; }
    else      { gc[i] = xc_on[(b * HH * WW + ix0 + row - 16) * 2 + 1]; ga[i] = ax; }
  }

  // ---- A-build mapping: 2x2 m-block (iy pair x ix pair) x 8 k per thread
  const int kg = tid & 7;          // k = 8*kg
  const int cc = (tid >> 3) & 3;   // ix_local = 2*cc + s
  const int aa = tid >> 5;         // iy_local = 2*aa + r

  // ---- Z staging mapping: d pair = 2*dp, k-groups wv4 and wv4+4
  const int dp  = tid & 63;
  const int wv4 = tid >> 6;

  // ---- consumer mapping
  const int lane = tid & 63;
  const int wv = tid >> 6;
  const int wm = wv >> 1, wd = wv & 1;
  const int i16 = lane & 15, quad = lane >> 4;

  v4f acc[4][4];
  #pragma unroll
  for (int t = 0; t < 4; ++t)
    #pragma unroll
    for (int d = 0; d < 4; ++d)
      acc[t][d] = (v4f){0.f, 0.f, 0.f, 0.f};

  const float* xb = xc_off + (size_t)b * NN * 2;
  const float* zb = zc_off + (size_t)b * NN * DZc;

  // ---- prologue: stage gtab(kt=0) into buf 0
  {
    const int n0 = kt0 * BK;
    float2 xo = *(const float2*)&xb[(size_t)(n0 + gk) * 2];
    #pragma unroll
    for (int i = 0; i < 6; ++i){
      float x = (i < 4) ? xo.x : xo.y;
      float d = gc[i] - x;
      gtab[0][grow0 + 4 * i][gk] = fexp2(ga[i] * d * d);
    }
  }

  #pragma unroll 1
  for (int kt = 0; kt < nkt; ++kt){
    const int n0 = (kt0 + kt) * BK;
    const int buf = kt & 1;
    __syncthreads();   // gtab(kt) ready; previous consume done (A/Z reusable)

    // ---- Z global loads first (vmcnt fill): 16 coalesced float2 row-reads
    float2 zl[2][8];
    #pragma unroll
    for (int kk = 0; kk < 2; ++kk)
      #pragma unroll
      for (int r = 0; r < 8; ++r)
        zl[kk][r] = *(const float2*)&zb[(size_t)(n0 + 8 * (wv4 + 4 * kk) + r) * DZc + 2 * dp];

    // ---- A-build: read gtab, 32 products, write 4 b128 to At
    {
      float4 gy[2][2], gx[2][2];
      #pragma unroll
      for (int r = 0; r < 2; ++r){
        gy[r][0] = *(const float4*)&gtab[buf][2 * aa + r][8 * kg];
        gy[r][1] = *(const float4*)&gtab[buf][2 * aa + r][8 * kg + 4];
        gx[r][0] = *(const float4*)&gtab[buf][16 + 2 * cc + r][8 * kg];
        gx[r][1] = *(const float4*)&gtab[buf][16 + 2 * cc + r][8 * kg + 4];
      }
      #pragma unroll
      for (int r = 0; r < 2; ++r){
        #pragma unroll
        for (int s = 0; s < 2; ++s){
          const int m = (2 * aa + r) * 8 + 2 * cc + s;
          union { unsigned u[4]; v8s v; } af;
          af.u[0] = pack2(gy[r][0].x * gx[s][0].x, gy[r][0].y * gx[s][0].y);
          af.u[1] = pack2(gy[r][0].z * gx[s][0].z, gy[r][0].w * gx[s][0].w);
          af.u[2] = pack2(gy[r][1].x * gx[s][1].x, gy[r][1].y * gx[s][1].y);
          af.u[3] = pack2(gy[r][1].z * gx[s][1].z, gy[r][1].w * gx[s][1].w);
          *(v8s*)&At[m][8 * kg] = af.v;
        }
      }
    }

    // ---- Z transpose-pack: 4 b128 writes
    #pragma unroll
    for (int kk = 0; kk < 2; ++kk){
      const int kb = 8 * (wv4 + 4 * kk);
      union { unsigned u[4]; v8s v; } ze, zo;
      #pragma unroll
      for (int j = 0; j < 4; ++j){
        ze.u[j] = pack2(zl[kk][2 * j].x, zl[kk][2 * j + 1].x);
        zo.u[j] = pack2(zl[kk][2 * j].y, zl[kk][2 * j + 1].y);
      }
      *(v8s*)&zt[2 * dp][kb]     = ze.v;
      *(v8s*)&zt[2 * dp + 1][kb] = zo.v;
    }

    __syncthreads();   // At, zt ready

    // ---- stage next gtab's global load early (drains during MFMA)
    const bool have_next = (kt + 1 < nkt);
    float2 xo_n = (float2){0.f, 0.f};
    if (have_next) xo_n = *(const float2*)&xb[(size_t)(n0 + BK + gk) * 2];

    // ---- consume: 32 MFMA, 16 b128 reads
    #pragma unroll
    for (int kstep = 0; kstep < 2; ++kstep){
      const int kq = kstep * 32 + quad * 8;
      v8s bf[4];
      #pragma unroll
      for (int dt = 0; dt < 4; ++dt)
        bf[dt] = *(const v8s*)&zt[wd * 64 + dt * 16 + i16][kq];
      #pragma unroll
      for (int t = 0; t < 4; ++t){
        v8s af = *(const v8s*)&At[wm * 64 + t * 16 + i16][kq];
        #pragma unroll
        for (int dt = 0; dt < 4; ++dt)
          acc[t][dt] = __builtin_amdgcn_mfma_f32_16x16x32_bf16(af, bf[dt], acc[t][dt], 0, 0, 0);
      }
    }

    // ---- gtab(kt+1) -> other buffer (read after next barrier)
    if (have_next){
      #pragma unroll
      for (int i = 0; i < 6; ++i){
        float x = (i < 4) ? xo_n.x : xo_n.y;
        float d = gc[i] - x;
        gtab[buf ^ 1][grow0 + 4 * i][gk] = fexp2(ga[i] * d * d);
      }
    }
  }

  // ---- epilogue: atomic accumulate K-split partials
  #pragma unroll
  for (int t = 0; t < 4; ++t){
    #pragma unroll
    for (int dt = 0; dt < 4; ++dt){
      const int d = wd * 64 + dt * 16 + i16;
      #pragma unroll
      for (int r = 0; r < 4; ++r){
        const int ml = wm * 64 + t * 16 + quad * 4 + r;
        const int iy = iy0 + (ml >> 3);
        const int ix = ix0 + (ml & 7);
        unsafeAtomicAdd(&out[((b * HH + iy) * WW + ix) * DZc + d], acc[t][dt][r]);
      }
    }
  }
}

extern "C" void kernel_launch(void* const* d_in, const int* in_sizes, int n_in,
                              void* d_out, int out_size, void* d_ws, size_t ws_size,
                              hipStream_t stream){
  const float* xc_off = (const float*)d_in[0];
  const float* xc_on  = (const float*)d_in[1];
  const float* zc_off = (const float*)d_in[2];
  const float* zc_on  = (const float*)d_in[3];
  const float* lsp    = (const float*)d_in[4];
  const int*   ign    = (const int*)d_in[5];
  float* out = (float*)d_out;

  init_out_kernel<<<out_size / 1024, 256, 0, stream>>>((const float4*)zc_on, ign, (float4*)out);
  setconv_gemm_kernel<<<4 * 32 * KSPLIT, 256, 0, stream>>>(xc_off, xc_on, zc_off, lsp, out);
}

// Round 3
// 143.803 us; speedup vs baseline: 1.2792x; 1.2792x over previous
//
#include <hip/hip_runtime.h>

#define HH 64
#define WW 64
#define NN 4096
#define DZc 128
#define KS 8
#define BK 64
#define NKT (NN / KS / BK)   // 8 k-tiles per block

typedef short v4sh __attribute__((ext_vector_type(4)));
typedef short v8s  __attribute__((ext_vector_type(8)));
typedef float v16f __attribute__((ext_vector_type(16)));

__device__ __forceinline__ unsigned asu(float f){
  union { float f; unsigned u; } c; c.f = f; return c.u;
}
// rounded bf16 pack (for Z): lo -> low16, hi -> high16
__device__ __forceinline__ unsigned pack2_rnd(float lo, float hi){
  return __builtin_amdgcn_perm(asu(hi) + 0x8000u, asu(lo) + 0x8000u, 0x07060302u);
}
// truncated bf16 pack (for A weights, saves 2 VALU ops in the hot loop)
__device__ __forceinline__ unsigned pack2_trunc(float lo, float hi){
  return __builtin_amdgcn_perm(asu(hi), asu(lo), 0x07060302u);
}
__device__ __forceinline__ float fexp2(float x){ return __builtin_amdgcn_exp2f(x); }

__global__ void init_out_kernel(const float4* __restrict__ zc_on,
                                const int* __restrict__ ignore,
                                float4* __restrict__ out){
  int i = blockIdx.x * blockDim.x + threadIdx.x;
  float4 v = zc_on[i];
  if (ignore[0]) { v.x = 0.f; v.y = 0.f; v.z = 0.f; v.w = 0.f; }
  out[i] = v;
}

// Grid: 512 blocks = ks(8, HIGH bits) x b(4) x mt(16).  ks in high bits =>
// the 8 K-split writers of each output line share blockIdx%8 => same XCD =>
// atomic lines stay in one L2 (fixes r2's 184MB write-through storm).
// Block: 256 thr = 4 waves; BM=256 (32iy x 8ix), BD=128, BK=64, 8 k-tiles.
// Wave: 64m x 128d via 2x4 tiles of 32x32x16 MFMA, acc 128 VGPR.
// Single barrier per k-tile, double-buffered zt + gtab; A built in registers.
__global__ __launch_bounds__(256, 2)
void setconv_gemm_kernel(const float* __restrict__ xc_off,
                         const float* __restrict__ xc_on,
                         const float* __restrict__ zc_off,
                         const float* __restrict__ lsp,
                         float* __restrict__ out)
{
  __shared__ unsigned short zt[2][128][68];  // Z^T bf16 [d][k], row 136B (8B-aligned, stride 34 dw -> 2-way=free)
  __shared__ float gtab[2][40][68];          // rows 0-31: gy per iy, 32-39: gx per ix

  const int tid = threadIdx.x;
  const int bid = blockIdx.x;
  const int ks  = bid >> 6;          // HIGH bits
  const int bm  = bid & 63;
  const int b   = bm >> 4;
  const int mt  = bm & 15;
  const int iy0 = (mt >> 3) * 32;
  const int ix0 = (mt & 7) * 8;
  const int nbase = ks * (NN / KS);

  const float lsy = 1e-5f + log1pf(expf(lsp[0]));
  const float lsx = 1e-5f + log1pf(expf(lsp[1]));
  const float LOG2E = 1.44269504088896340736f;
  const float ay = -0.5f * LOG2E / (lsy * lsy);
  const float ax = -0.5f * LOG2E / (lsx * lsx);

  // ---- gtab staging: 40 rows x 64 cols / 256 thr = 10 values per thread
  const int gk = tid & 63;
  const int r0 = tid >> 6;
  float gc[10], ga[10];
  #pragma unroll
  for (int i = 0; i < 10; ++i){
    int row = r0 + 4 * i;
    if (row < 32){ gc[i] = xc_on[((b * HH + iy0 + row) * WW) * 2];        ga[i] = ay; }
    else         { gc[i] = xc_on[(b * HH * WW + ix0 + row - 32) * 2 + 1]; ga[i] = ax; }
  }

  // ---- Z staging: thread owns one d-row (lane-contig => conflict-free writes), 32 k
  const int zd  = (tid & 63) | (((tid >> 6) & 1) << 6);
  const int zkh = tid >> 7;   // k-half 0/1

  // ---- consumer mapping
  const int lane = tid & 63;
  const int wv  = tid >> 6;
  const int l31 = lane & 31;
  const int lh  = lane >> 5;
  const int gxrow = 32 + (l31 & 7);
  const int gyrow0 = wv * 8 + (l31 >> 3);   // + mtl*4

  v16f acc[2][4];
  #pragma unroll
  for (int m = 0; m < 2; ++m)
    #pragma unroll
    for (int d = 0; d < 4; ++d)
      #pragma unroll
      for (int r = 0; r < 16; ++r)
        acc[m][d][r] = 0.f;

  const float* xb = xc_off + (size_t)b * NN * 2;
  const float* zb = zc_off + (size_t)b * NN * DZc;

  // ---- prologue: stage k-tile 0 into buf 0
  {
    const int n0 = nbase;
    float2 xo = *(const float2*)&xb[(size_t)(n0 + gk) * 2];
    #pragma unroll
    for (int i = 0; i < 10; ++i){
      float dd = gc[i] - ((r0 + 4 * i < 32) ? xo.x : xo.y);
      gtab[0][r0 + 4 * i][gk] = fexp2(ga[i] * dd * dd);
    }
    float zv[32];
    #pragma unroll
    for (int i = 0; i < 32; ++i)
      zv[i] = zb[(size_t)(n0 + zkh * 32 + i) * DZc + zd];
    #pragma unroll
    for (int j = 0; j < 8; ++j){
      union { unsigned u[2]; v4sh v; } w;
      w.u[0] = pack2_rnd(zv[4 * j],     zv[4 * j + 1]);
      w.u[1] = pack2_rnd(zv[4 * j + 2], zv[4 * j + 3]);
      *(v4sh*)&zt[0][zd][zkh * 32 + 4 * j] = w.v;
    }
  }
  __syncthreads();

  #pragma unroll 1
  for (int kt = 0; kt < NKT; ++kt){
    const int buf  = kt & 1;
    const int nbuf = buf ^ 1;
    const bool have_next = (kt + 1 < NKT);
    const int n1 = nbase + (kt + 1) * BK;

    // ---- issue next tile's global loads early (drain during ksteps 0-1)
    float zv[32];
    float2 xo_n = (float2){0.f, 0.f};
    if (have_next){
      #pragma unroll
      for (int i = 0; i < 32; ++i)
        zv[i] = zb[(size_t)(n1 + zkh * 32 + i) * DZc + zd];
      xo_n = *(const float2*)&xb[(size_t)(n1 + gk) * 2];
    }

    // ---- consume ksteps 0-1
    #pragma unroll
    for (int kstep = 0; kstep < 2; ++kstep){
      const int k0 = kstep * 16 + lh * 8;
      const float4 xA = *(const float4*)&gtab[buf][gxrow][k0];
      const float4 xB = *(const float4*)&gtab[buf][gxrow][k0 + 4];
      v8s bf[4];
      #pragma unroll
      for (int dtl = 0; dtl < 4; ++dtl){
        union { v4sh h[2]; v8s v; } u;
        u.h[0] = *(const v4sh*)&zt[buf][dtl * 32 + l31][k0];
        u.h[1] = *(const v4sh*)&zt[buf][dtl * 32 + l31][k0 + 4];
        bf[dtl] = u.v;
      }
      #pragma unroll
      for (int mtl = 0; mtl < 2; ++mtl){
        const float4 gA = *(const float4*)&gtab[buf][gyrow0 + mtl * 4][k0];
        const float4 gB = *(const float4*)&gtab[buf][gyrow0 + mtl * 4][k0 + 4];
        union { unsigned u[4]; v8s v; } af;
        af.u[0] = pack2_trunc(gA.x * xA.x, gA.y * xA.y);
        af.u[1] = pack2_trunc(gA.z * xA.z, gA.w * xA.w);
        af.u[2] = pack2_trunc(gB.x * xB.x, gB.y * xB.y);
        af.u[3] = pack2_trunc(gB.z * xB.z, gB.w * xB.w);
        #pragma unroll
        for (int dtl = 0; dtl < 4; ++dtl)
          acc[mtl][dtl] = __builtin_amdgcn_mfma_f32_32x32x16_bf16(af.v, bf[dtl], acc[mtl][dtl], 0, 0, 0);
      }
    }

    // ---- stage next Z into other buffer (safe: barrier at end of PREVIOUS iter
    //      guarantees all waves finished reading nbuf)
    if (have_next){
      #pragma unroll
      for (int j = 0; j < 8; ++j){
        union { unsigned u[2]; v4sh v; } w;
        w.u[0] = pack2_rnd(zv[4 * j],     zv[4 * j + 1]);
        w.u[1] = pack2_rnd(zv[4 * j + 2], zv[4 * j + 3]);
        *(v4sh*)&zt[nbuf][zd][zkh * 32 + 4 * j] = w.v;
      }
    }

    // ---- consume ksteps 2-3
    #pragma unroll
    for (int kstep = 2; kstep < 4; ++kstep){
      const int k0 = kstep * 16 + lh * 8;
      const float4 xA = *(const float4*)&gtab[buf][gxrow][k0];
      const float4 xB = *(const float4*)&gtab[buf][gxrow][k0 + 4];
      v8s bf[4];
      #pragma unroll
      for (int dtl = 0; dtl < 4; ++dtl){
        union { v4sh h[2]; v8s v; } u;
        u.h[0] = *(const v4sh*)&zt[buf][dtl * 32 + l31][k0];
        u.h[1] = *(const v4sh*)&zt[buf][dtl * 32 + l31][k0 + 4];
        bf[dtl] = u.v;
      }
      #pragma unroll
      for (int mtl = 0; mtl < 2; ++mtl){
        const float4 gA = *(const float4*)&gtab[buf][gyrow0 + mtl * 4][k0];
        const float4 gB = *(const float4*)&gtab[buf][gyrow0 + mtl * 4][k0 + 4];
        union { unsigned u[4]; v8s v; } af;
        af.u[0] = pack2_trunc(gA.x * xA.x, gA.y * xA.y);
        af.u[1] = pack2_trunc(gA.z * xA.z, gA.w * xA.w);
        af.u[2] = pack2_trunc(gB.x * xB.x, gB.y * xB.y);
        af.u[3] = pack2_trunc(gB.z * xB.z, gB.w * xB.w);
        #pragma unroll
        for (int dtl = 0; dtl < 4; ++dtl)
          acc[mtl][dtl] = __builtin_amdgcn_mfma_f32_32x32x16_bf16(af.v, bf[dtl], acc[mtl][dtl], 0, 0, 0);
      }
    }

    // ---- stage next gtab
    if (have_next){
      #pragma unroll
      for (int i = 0; i < 10; ++i){
        float dd = gc[i] - ((r0 + 4 * i < 32) ? xo_n.x : xo_n.y);
        gtab[nbuf][r0 + 4 * i][gk] = fexp2(ga[i] * dd * dd);
      }
    }
    __syncthreads();
  }

  // ---- epilogue: K-split partials via XCD-local atomics
  // C/D of 32x32: col = lane&31 (d), row = (reg&3) + 8*(reg>>2) + 4*(lane>>5)
  #pragma unroll
  for (int mtl = 0; mtl < 2; ++mtl){
    #pragma unroll
    for (int dtl = 0; dtl < 4; ++dtl){
      const int d = dtl * 32 + l31;
      #pragma unroll
      for (int reg = 0; reg < 16; ++reg){
        const int row = (reg & 3) + 8 * (reg >> 2) + 4 * lh;
        const int m = wv * 64 + mtl * 32 + row;
        const int iy = iy0 + (m >> 3);
        const int ix = ix0 + (m & 7);
        unsafeAtomicAdd(&out[((b * HH + iy) * WW + ix) * DZc + d], acc[mtl][dtl][reg]);
      }
    }
  }
}

extern "C" void kernel_launch(void* const* d_in, const int* in_sizes, int n_in,
                              void* d_out, int out_size, void* d_ws, size_t ws_size,
                              hipStream_t stream){
  const float* xc_off = (const float*)d_in[0];
  const float* xc_on  = (const float*)d_in[1];
  const float* zc_off = (const float*)d_in[2];
  const float* zc_on  = (const float*)d_in[3];
  const float* lsp    = (const float*)d_in[4];
  const int*   ign    = (const int*)d_in[5];
  float* out = (float*)d_out;

  init_out_kernel<<<out_size / 1024, 256, 0, stream>>>((const float4*)zc_on, ign, (float4*)out);
  setconv_gemm_kernel<<<KS * 64, 256, 0, stream>>>(xc_off, xc_on, zc_off, lsp, out);
}

// Round 5
// 115.668 us; speedup vs baseline: 1.5904x; 1.2432x over previous
//
#include <hip/hip_runtime.h>

#define HH 64
#define WW 64
#define NN 4096
#define DZc 128
#define KS 8
#define BK 64
#define NKT (NN / KS / BK)        // 8 k-tiles per block
#define CELLS 2097152             // 4*64*64*128 output floats
#define WS_NEED (8ull * CELLS * 4ull)

typedef __fp16 v2fp16 __attribute__((ext_vector_type(2)));
typedef _Float16 v4h __attribute__((ext_vector_type(4)));
typedef _Float16 v8h __attribute__((ext_vector_type(8)));
typedef float v16f __attribute__((ext_vector_type(16)));

__device__ __forceinline__ unsigned pk16(float lo, float hi){
  union { v2fp16 h; unsigned u; } c;
  c.h = __builtin_amdgcn_cvt_pkrtz(lo, hi);
  return c.u;
}
__device__ __forceinline__ float fexp2(float x){ return __builtin_amdgcn_exp2f(x); }

__global__ void init_out_kernel(const float4* __restrict__ zc_on,
                                const int* __restrict__ ignore,
                                float4* __restrict__ out){
  int i = blockIdx.x * blockDim.x + threadIdx.x;
  float4 v = zc_on[i];
  if (ignore[0]) { v.x = 0.f; v.y = 0.f; v.z = 0.f; v.w = 0.f; }
  out[i] = v;
}

// sum 8 K-split partials + zc_on -> out (float4 per thread, fully coalesced)
__global__ void reduce_kernel(const float4* __restrict__ part,
                              const float4* __restrict__ zc_on,
                              const int* __restrict__ ignore,
                              float4* __restrict__ out){
  int i = blockIdx.x * blockDim.x + threadIdx.x;
  float4 s = zc_on[i];
  if (ignore[0]) { s.x = 0.f; s.y = 0.f; s.z = 0.f; s.w = 0.f; }
  #pragma unroll
  for (int ks = 0; ks < KS; ++ks){
    float4 p = part[(size_t)ks * (CELLS / 4) + i];
    s.x += p.x; s.y += p.y; s.z += p.z; s.w += p.w;
  }
  out[i] = s;
}

// Grid: 512 blocks = ks(8, HIGH bits => same-XCD writer groups) x b(4) x mt(16).
// Block: 256 thr = 4 waves; BM=256 (32iy x 8ix), BD=128, BK=64, 8 k-tiles.
// Wave: 64m x 128d via 2x4 tiles of 32x32x16 f16 MFMA.
// Epilogue: part!=null -> plain stores of K-split partials to ws (NO atomics);
//           else r3-style f32 atomics into out (fallback when ws too small).
__global__ __launch_bounds__(256, 2)
void setconv_gemm_kernel(const float* __restrict__ xc_off,
                         const float* __restrict__ xc_on,
                         const float* __restrict__ zc_off,
                         const float* __restrict__ lsp,
                         float* __restrict__ part,
                         float* __restrict__ out)
{
  __shared__ unsigned short zt[2][128][68];  // Z^T f16 [d][k], stride 34 dw (r3: 0 conflicts)
  __shared__ unsigned short gt[2][40][68];   // f16 g-tables: rows 0-31 gy, 32-39 gx

  const int tid = threadIdx.x;
  const int bid = blockIdx.x;
  const int ks  = bid >> 6;
  const int bm  = bid & 63;
  const int b   = bm >> 4;
  const int mt  = bm & 15;
  const int iy0 = (mt >> 3) * 32;
  const int ix0 = (mt & 7) * 8;
  const int nbase = ks * (NN / KS);

  const float lsy = 1e-5f + log1pf(expf(lsp[0]));
  const float lsx = 1e-5f + log1pf(expf(lsp[1]));
  const float LOG2E = 1.44269504088896340736f;
  const float ay = -0.5f * LOG2E / (lsy * lsy);
  const float ax = -0.5f * LOG2E / (lsx * lsx);

  // ---- gtab staging: 40 rows x 32 col-pairs; thread -> col-pair gp, rows gr+8i
  const int gp = tid & 31;         // k-pair
  const int gr = tid >> 5;         // row base (0..7)
  float gc[5], ga[5];
  #pragma unroll
  for (int i = 0; i < 5; ++i){
    int row = gr + 8 * i;
    if (row < 32){ gc[i] = xc_on[((b * HH + iy0 + row) * WW) * 2];        ga[i] = ay; }
    else         { gc[i] = xc_on[(b * HH * WW + ix0 + row - 32) * 2 + 1]; ga[i] = ax; }
  }

  // ---- Z staging: thread owns d-row zd, k-half zkh (r3 mapping: 0 conflicts)
  const int zd  = (tid & 63) | (((tid >> 6) & 1) << 6);
  const int zkh = tid >> 7;

  // ---- consumer mapping
  const int lane = tid & 63;
  const int wv  = tid >> 6;
  const int l31 = lane & 31;
  const int lh  = lane >> 5;
  const int gxr = 32 + (l31 & 7);
  const int gyr = wv * 8 + (l31 >> 3);     // + mtl*4

  v16f acc[2][4];
  #pragma unroll
  for (int m = 0; m < 2; ++m)
    #pragma unroll
    for (int d = 0; d < 4; ++d)
      #pragma unroll
      for (int r = 0; r < 16; ++r)
        acc[m][d][r] = 0.f;

  const float* xb = xc_off + (size_t)b * NN * 2;
  const float* zb = zc_off + (size_t)b * NN * DZc;

  // ---- prologue: stage k-tile 0 into buf 0
  {
    const int n0 = nbase;
    float4 xq = *(const float4*)&xb[(size_t)(n0 + 2 * gp) * 2];
    unsigned* gw = (unsigned*)&gt[0][0][0];
    #pragma unroll
    for (int i = 0; i < 5; ++i){
      int row = gr + 8 * i;
      float s0 = (row < 32) ? xq.x : xq.y;
      float s1 = (row < 32) ? xq.z : xq.w;
      float d0 = gc[i] - s0, d1 = gc[i] - s1;
      gw[row * 34 + gp] = pk16(fexp2(ga[i] * d0 * d0), fexp2(ga[i] * d1 * d1));
    }
    float zv[32];
    #pragma unroll
    for (int i = 0; i < 32; ++i)
      zv[i] = zb[(size_t)(n0 + zkh * 32 + i) * DZc + zd];
    #pragma unroll
    for (int j = 0; j < 8; ++j){
      union { unsigned u[2]; double d; } w;
      w.u[0] = pk16(zv[4 * j],     zv[4 * j + 1]);
      w.u[1] = pk16(zv[4 * j + 2], zv[4 * j + 3]);
      *(double*)&zt[0][zd][zkh * 32 + 4 * j] = w.d;
    }
  }
  __syncthreads();

  #pragma unroll 1
  for (int kt = 0; kt < NKT; ++kt){
    const int buf  = kt & 1;
    const int nbuf = buf ^ 1;
    const bool have_next = (kt + 1 < NKT);
    const int n1 = nbase + (kt + 1) * BK;

    // ---- issue next tile's global loads early
    float zv[32];
    float4 xq_n = (float4){0.f, 0.f, 0.f, 0.f};
    if (have_next){
      #pragma unroll
      for (int i = 0; i < 32; ++i)
        zv[i] = zb[(size_t)(n1 + zkh * 32 + i) * DZc + zd];
      xq_n = *(const float4*)&xb[(size_t)(n1 + 2 * gp) * 2];
    }

    // ---- consume ksteps 0-1
    #pragma unroll
    for (int kstep = 0; kstep < 2; ++kstep){
      const int k0 = kstep * 16 + lh * 8;
      union { v4h h[2]; v8h v; } xu;
      xu.h[0] = *(const v4h*)&gt[buf][gxr][k0];
      xu.h[1] = *(const v4h*)&gt[buf][gxr][k0 + 4];
      v8h bfr[4];
      #pragma unroll
      for (int dtl = 0; dtl < 4; ++dtl){
        union { v4h h[2]; v8h v; } zu;
        zu.h[0] = *(const v4h*)&zt[buf][dtl * 32 + l31][k0];
        zu.h[1] = *(const v4h*)&zt[buf][dtl * 32 + l31][k0 + 4];
        bfr[dtl] = zu.v;
      }
      #pragma unroll
      for (int mtl = 0; mtl < 2; ++mtl){
        union { v4h h[2]; v8h v; } yu;
        yu.h[0] = *(const v4h*)&gt[buf][gyr + mtl * 4][k0];
        yu.h[1] = *(const v4h*)&gt[buf][gyr + mtl * 4][k0 + 4];
        v8h av = yu.v * xu.v;   // 4x v_pk_mul_f16
        #pragma unroll
        for (int dtl = 0; dtl < 4; ++dtl)
          acc[mtl][dtl] = __builtin_amdgcn_mfma_f32_32x32x16_f16(av, bfr[dtl], acc[mtl][dtl], 0, 0, 0);
      }
    }

    // ---- stage next Z into other buffer
    if (have_next){
      #pragma unroll
      for (int j = 0; j < 8; ++j){
        union { unsigned u[2]; double d; } w;
        w.u[0] = pk16(zv[4 * j],     zv[4 * j + 1]);
        w.u[1] = pk16(zv[4 * j + 2], zv[4 * j + 3]);
        *(double*)&zt[nbuf][zd][zkh * 32 + 4 * j] = w.d;
      }
    }

    // ---- consume ksteps 2-3
    #pragma unroll
    for (int kstep = 2; kstep < 4; ++kstep){
      const int k0 = kstep * 16 + lh * 8;
      union { v4h h[2]; v8h v; } xu;
      xu.h[0] = *(const v4h*)&gt[buf][gxr][k0];
      xu.h[1] = *(const v4h*)&gt[buf][gxr][k0 + 4];
      v8h bfr[4];
      #pragma unroll
      for (int dtl = 0; dtl < 4; ++dtl){
        union { v4h h[2]; v8h v; } zu;
        zu.h[0] = *(const v4h*)&zt[buf][dtl * 32 + l31][k0];
        zu.h[1] = *(const v4h*)&zt[buf][dtl * 32 + l31][k0 + 4];
        bfr[dtl] = zu.v;
      }
      #pragma unroll
      for (int mtl = 0; mtl < 2; ++mtl){
        union { v4h h[2]; v8h v; } yu;
        yu.h[0] = *(const v4h*)&gt[buf][gyr + mtl * 4][k0];
        yu.h[1] = *(const v4h*)&gt[buf][gyr + mtl * 4][k0 + 4];
        v8h av = yu.v * xu.v;
        #pragma unroll
        for (int dtl = 0; dtl < 4; ++dtl)
          acc[mtl][dtl] = __builtin_amdgcn_mfma_f32_32x32x16_f16(av, bfr[dtl], acc[mtl][dtl], 0, 0, 0);
      }
    }

    // ---- stage next gtab
    if (have_next){
      unsigned* gw = (unsigned*)&gt[nbuf][0][0];
      #pragma unroll
      for (int i = 0; i < 5; ++i){
        int row = gr + 8 * i;
        float s0 = (row < 32) ? xq_n.x : xq_n.y;
        float s1 = (row < 32) ? xq_n.z : xq_n.w;
        float d0 = gc[i] - s0, d1 = gc[i] - s1;
        gw[row * 34 + gp] = pk16(fexp2(ga[i] * d0 * d0), fexp2(ga[i] * d1 * d1));
      }
    }
    __syncthreads();
  }

  // ---- epilogue
  // C/D of 32x32: col = lane&31 (d), row = (reg&3) + 8*(reg>>2) + 4*(lane>>5)
  if (part){
    float* pw = part + (size_t)ks * CELLS;
    #pragma unroll
    for (int mtl = 0; mtl < 2; ++mtl)
      #pragma unroll
      for (int dtl = 0; dtl < 4; ++dtl){
        const int d = dtl * 32 + l31;
        #pragma unroll
        for (int reg = 0; reg < 16; ++reg){
          const int row = (reg & 3) + 8 * (reg >> 2) + 4 * lh;
          const int m = wv * 64 + mtl * 32 + row;
          const int iy = iy0 + (m >> 3);
          const int ix = ix0 + (m & 7);
          pw[((b * HH + iy) * WW + ix) * DZc + d] = acc[mtl][dtl][reg];
        }
      }
  } else {
    #pragma unroll
    for (int mtl = 0; mtl < 2; ++mtl)
      #pragma unroll
      for (int dtl = 0; dtl < 4; ++dtl){
        const int d = dtl * 32 + l31;
        #pragma unroll
        for (int reg = 0; reg < 16; ++reg){
          const int row = (reg & 3) + 8 * (reg >> 2) + 4 * lh;
          const int m = wv * 64 + mtl * 32 + row;
          const int iy = iy0 + (m >> 3);
          const int ix = ix0 + (m & 7);
          unsafeAtomicAdd(&out[((b * HH + iy) * WW + ix) * DZc + d], acc[mtl][dtl][reg]);
        }
      }
  }
}

extern "C" void kernel_launch(void* const* d_in, const int* in_sizes, int n_in,
                              void* d_out, int out_size, void* d_ws, size_t ws_size,
                              hipStream_t stream){
  const float* xc_off = (const float*)d_in[0];
  const float* xc_on  = (const float*)d_in[1];
  const float* zc_off = (const float*)d_in[2];
  const float* zc_on  = (const float*)d_in[3];
  const float* lsp    = (const float*)d_in[4];
  const int*   ign    = (const int*)d_in[5];
  float* out = (float*)d_out;

  if (ws_size >= WS_NEED){
    float* part = (float*)d_ws;
    setconv_gemm_kernel<<<KS * 64, 256, 0, stream>>>(xc_off, xc_on, zc_off, lsp, part, out);
    reduce_kernel<<<CELLS / 4 / 256, 256, 0, stream>>>((const float4*)part, (const float4*)zc_on, ign, (float4*)out);
  } else {
    init_out_kernel<<<out_size / 1024, 256, 0, stream>>>((const float4*)zc_on, ign, (float4*)out);
    setconv_gemm_kernel<<<KS * 64, 256, 0, stream>>>(xc_off, xc_on, zc_off, lsp, nullptr, out);
  }
}

// Round 6
// 108.925 us; speedup vs baseline: 1.6888x; 1.0619x over previous
//
#include <hip/hip_runtime.h>

#define HH 64
#define WW 64
#define NN 4096
#define DZc 128
#define KS 8
#define BK 64
#define NKT (NN / KS / BK)        // 8 k-tiles per block
#define CELLS 2097152             // 4*64*64*128 output floats
#define WS_NEED (8ull * CELLS * 2ull)   // f16 partials: 32 MB

typedef __fp16 v2fp16 __attribute__((ext_vector_type(2)));
typedef _Float16 v4h __attribute__((ext_vector_type(4)));
typedef _Float16 v8h __attribute__((ext_vector_type(8)));
typedef float v16f __attribute__((ext_vector_type(16)));

__device__ __forceinline__ unsigned pk16(float lo, float hi){
  union { v2fp16 h; unsigned u; } c;
  c.h = __builtin_amdgcn_cvt_pkrtz(lo, hi);
  return c.u;
}
__device__ __forceinline__ float fexp2(float x){ return __builtin_amdgcn_exp2f(x); }

__global__ void init_out_kernel(const float4* __restrict__ zc_on,
                                const int* __restrict__ ignore,
                                float4* __restrict__ out){
  int i = blockIdx.x * blockDim.x + threadIdx.x;
  float4 v = zc_on[i];
  if (ignore[0]) { v.x = 0.f; v.y = 0.f; v.z = 0.f; v.w = 0.f; }
  out[i] = v;
}

// sum 8 f16 K-split partials + zc_on -> out (coalesced v4h loads, float4 store)
__global__ void reduce_kernel(const v4h* __restrict__ part,
                              const float4* __restrict__ zc_on,
                              const int* __restrict__ ignore,
                              float4* __restrict__ out){
  int i = blockIdx.x * blockDim.x + threadIdx.x;
  float4 s = zc_on[i];
  if (ignore[0]) { s.x = 0.f; s.y = 0.f; s.z = 0.f; s.w = 0.f; }
  #pragma unroll
  for (int ks = 0; ks < KS; ++ks){
    v4h p = part[(size_t)ks * (CELLS / 4) + i];
    s.x += (float)p[0]; s.y += (float)p[1]; s.z += (float)p[2]; s.w += (float)p[3];
  }
  out[i] = s;
}

// Grid: 512 blocks = ks(8, HIGH bits) x b(4) x mt(16).
// Block: 256 thr = 4 waves; BM=256 (32iy x 8ix), BD=128, BK=64, 8 k-tiles.
// Wave: 64m x 128d via 2x4 tiles of 32x32x16 f16 MFMA.
// k-loop: [loads kt+1] [consume all 4 ksteps of kt] [pack Z kt+1] [gtab kt+1] [barrier]
//   -> Z vmcnt wait covered by the full consume phase.
// Epilogue: f16 partial stores to ws (no atomics); f32-atomic fallback if ws small.
__global__ __launch_bounds__(256, 2)
void setconv_gemm_kernel(const float* __restrict__ xc_off,
                         const float* __restrict__ xc_on,
                         const float* __restrict__ zc_off,
                         const float* __restrict__ lsp,
                         _Float16* __restrict__ part,
                         float* __restrict__ out)
{
  __shared__ unsigned short zt[2][128][68];  // Z^T f16 [d][k], stride 34 dw (measured 0 conflicts; b64 reads 2-way=free)
  __shared__ unsigned short gt[2][40][72];   // f16 g-tables, stride 36 dw (16B-aligned rows -> b128 reads; few distinct rows -> broadcast)

  const int tid = threadIdx.x;
  const int bid = blockIdx.x;
  const int ks  = bid >> 6;
  const int bm  = bid & 63;
  const int b   = bm >> 4;
  const int mt  = bm & 15;
  const int iy0 = (mt >> 3) * 32;
  const int ix0 = (mt & 7) * 8;
  const int nbase = ks * (NN / KS);

  const float lsy = 1e-5f + log1pf(expf(lsp[0]));
  const float lsx = 1e-5f + log1pf(expf(lsp[1]));
  const float LOG2E = 1.44269504088896340736f;
  const float ay = -0.5f * LOG2E / (lsy * lsy);
  const float ax = -0.5f * LOG2E / (lsx * lsx);

  // ---- gtab staging: 40 rows x 32 col-pairs; thread -> col-pair gp, rows gr+8i
  const int gp = tid & 31;
  const int gr = tid >> 5;
  float gc[5], ga[5];
  #pragma unroll
  for (int i = 0; i < 5; ++i){
    int row = gr + 8 * i;
    if (row < 32){ gc[i] = xc_on[((b * HH + iy0 + row) * WW) * 2];        ga[i] = ay; }
    else         { gc[i] = xc_on[(b * HH * WW + ix0 + row - 32) * 2 + 1]; ga[i] = ax; }
  }

  // ---- Z staging: thread owns d-row zd, k-half zkh (measured 0 conflicts)
  const int zd  = (tid & 63) | (((tid >> 6) & 1) << 6);
  const int zkh = tid >> 7;

  // ---- consumer mapping
  const int lane = tid & 63;
  const int wv  = tid >> 6;
  const int l31 = lane & 31;
  const int lh  = lane >> 5;
  const int gxr = 32 + (l31 & 7);
  const int gyr = wv * 8 + (l31 >> 3);     // + mtl*4

  v16f acc[2][4];
  #pragma unroll
  for (int m = 0; m < 2; ++m)
    #pragma unroll
    for (int d = 0; d < 4; ++d)
      #pragma unroll
      for (int r = 0; r < 16; ++r)
        acc[m][d][r] = 0.f;

  const float* xb = xc_off + (size_t)b * NN * 2;
  const float* zb = zc_off + (size_t)b * NN * DZc;

  // ---- prologue: stage k-tile 0 into buf 0
  {
    const int n0 = nbase;
    float4 xq = *(const float4*)&xb[(size_t)(n0 + 2 * gp) * 2];
    unsigned* gw = (unsigned*)&gt[0][0][0];
    #pragma unroll
    for (int i = 0; i < 5; ++i){
      int row = gr + 8 * i;
      float s0 = (row < 32) ? xq.x : xq.y;
      float s1 = (row < 32) ? xq.z : xq.w;
      float d0 = gc[i] - s0, d1 = gc[i] - s1;
      gw[row * 36 + gp] = pk16(fexp2(ga[i] * d0 * d0), fexp2(ga[i] * d1 * d1));
    }
    float zv[32];
    #pragma unroll
    for (int i = 0; i < 32; ++i)
      zv[i] = zb[(size_t)(n0 + zkh * 32 + i) * DZc + zd];
    #pragma unroll
    for (int j = 0; j < 8; ++j){
      union { unsigned u[2]; double d; } w;
      w.u[0] = pk16(zv[4 * j],     zv[4 * j + 1]);
      w.u[1] = pk16(zv[4 * j + 2], zv[4 * j + 3]);
      *(double*)&zt[0][zd][zkh * 32 + 4 * j] = w.d;
    }
  }
  __syncthreads();

  #pragma unroll 1
  for (int kt = 0; kt < NKT; ++kt){
    const int buf  = kt & 1;
    const int nbuf = buf ^ 1;
    const bool have_next = (kt + 1 < NKT);
    const int n1 = nbase + (kt + 1) * BK;

    // ---- issue next tile's global loads (drain across the whole consume phase)
    float zv[32];
    float4 xq_n = (float4){0.f, 0.f, 0.f, 0.f};
    if (have_next){
      #pragma unroll
      for (int i = 0; i < 32; ++i)
        zv[i] = zb[(size_t)(n1 + zkh * 32 + i) * DZc + zd];
      xq_n = *(const float4*)&xb[(size_t)(n1 + 2 * gp) * 2];
    }

    // ---- consume all 4 ksteps: A-operands via single b128, Z via b64 pairs
    #pragma unroll
    for (int kstep = 0; kstep < 4; ++kstep){
      const int k0 = kstep * 16 + lh * 8;
      const v8h xu = *(const v8h*)&gt[buf][gxr][k0];
      v8h bfr[4];
      #pragma unroll
      for (int dtl = 0; dtl < 4; ++dtl){
        union { v4h h[2]; v8h v; } zu;
        zu.h[0] = *(const v4h*)&zt[buf][dtl * 32 + l31][k0];
        zu.h[1] = *(const v4h*)&zt[buf][dtl * 32 + l31][k0 + 4];
        bfr[dtl] = zu.v;
      }
      #pragma unroll
      for (int mtl = 0; mtl < 2; ++mtl){
        const v8h yu = *(const v8h*)&gt[buf][gyr + mtl * 4][k0];
        v8h av = yu * xu;   // 4x v_pk_mul_f16
        #pragma unroll
        for (int dtl = 0; dtl < 4; ++dtl)
          acc[mtl][dtl] = __builtin_amdgcn_mfma_f32_32x32x16_f16(av, bfr[dtl], acc[mtl][dtl], 0, 0, 0);
      }
    }

    // ---- pack & write next Z (vmcnt wait lands here, after full consume)
    if (have_next){
      #pragma unroll
      for (int j = 0; j < 8; ++j){
        union { unsigned u[2]; double d; } w;
        w.u[0] = pk16(zv[4 * j],     zv[4 * j + 1]);
        w.u[1] = pk16(zv[4 * j + 2], zv[4 * j + 3]);
        *(double*)&zt[nbuf][zd][zkh * 32 + 4 * j] = w.d;
      }
      unsigned* gw = (unsigned*)&gt[nbuf][0][0];
      #pragma unroll
      for (int i = 0; i < 5; ++i){
        int row = gr + 8 * i;
        float s0 = (row < 32) ? xq_n.x : xq_n.y;
        float s1 = (row < 32) ? xq_n.z : xq_n.w;
        float d0 = gc[i] - s0, d1 = gc[i] - s1;
        gw[row * 36 + gp] = pk16(fexp2(ga[i] * d0 * d0), fexp2(ga[i] * d1 * d1));
      }
    }
    __syncthreads();
  }

  // ---- epilogue
  // C/D of 32x32: col = lane&31 (d), row = (reg&3) + 8*(reg>>2) + 4*(lane>>5)
  if (part){
    _Float16* pw = part + (size_t)ks * CELLS;
    #pragma unroll
    for (int mtl = 0; mtl < 2; ++mtl)
      #pragma unroll
      for (int dtl = 0; dtl < 4; ++dtl){
        const int d = dtl * 32 + l31;
        #pragma unroll
        for (int reg = 0; reg < 16; ++reg){
          const int row = (reg & 3) + 8 * (reg >> 2) + 4 * lh;
          const int m = wv * 64 + mtl * 32 + row;
          const int iy = iy0 + (m >> 3);
          const int ix = ix0 + (m & 7);
          pw[((b * HH + iy) * WW + ix) * DZc + d] = (_Float16)acc[mtl][dtl][reg];
        }
      }
  } else {
    #pragma unroll
    for (int mtl = 0; mtl < 2; ++mtl)
      #pragma unroll
      for (int dtl = 0; dtl < 4; ++dtl){
        const int d = dtl * 32 + l31;
        #pragma unroll
        for (int reg = 0; reg < 16; ++reg){
          const int row = (reg & 3) + 8 * (reg >> 2) + 4 * lh;
          const int m = wv * 64 + mtl * 32 + row;
          const int iy = iy0 + (m >> 3);
          const int ix = ix0 + (m & 7);
          unsafeAtomicAdd(&out[((b * HH + iy) * WW + ix) * DZc + d], acc[mtl][dtl][reg]);
        }
      }
  }
}

extern "C" void kernel_launch(void* const* d_in, const int* in_sizes, int n_in,
                              void* d_out, int out_size, void* d_ws, size_t ws_size,
                              hipStream_t stream){
  const float* xc_off = (const float*)d_in[0];
  const float* xc_on  = (const float*)d_in[1];
  const float* zc_off = (const float*)d_in[2];
  const float* zc_on  = (const float*)d_in[3];
  const float* lsp    = (const float*)d_in[4];
  const int*   ign    = (const int*)d_in[5];
  float* out = (float*)d_out;

  if (ws_size >= WS_NEED){
    _Float16* part = (_Float16*)d_ws;
    setconv_gemm_kernel<<<KS * 64, 256, 0, stream>>>(xc_off, xc_on, zc_off, lsp, part, out);
    reduce_kernel<<<CELLS / 4 / 256, 256, 0, stream>>>((const v4h*)part, (const float4*)zc_on, ign, (float4*)out);
  } else {
    init_out_kernel<<<out_size / 1024, 256, 0, stream>>>((const float4*)zc_on, ign, (float4*)out);
    setconv_gemm_kernel<<<KS * 64, 256, 0, stream>>>(xc_off, xc_on, zc_off, lsp, nullptr, out);
  }
}